// Round 18
// baseline (566.011 us; speedup 1.0000x reference)
//
#include <hip/hip_runtime.h>
#include <hip/hip_bf16.h>
#include <stdint.h>

// Encoder: B=2,S=2048,D=1024,HID=1024,NH=16,C=64,L=4. 4096 token-rows.
#define TOK 4096
#define DM  1024

using u16 = unsigned short;
typedef __attribute__((ext_vector_type(8))) short short8;   // bf16x8 frag (4 VGPR)
typedef __attribute__((ext_vector_type(4))) float f32x4;

__device__ __forceinline__ u16 f2bf(float f){
  unsigned u = __float_as_uint(f);
  return (u16)((u + 0x7fffu + ((u >> 16) & 1u)) >> 16);   // RNE
}
__device__ __forceinline__ float bf2f(u16 h){ return __uint_as_float(((unsigned)h) << 16); }

// raw hardware exp2 / rcp (skip OCML guards; args range-safe; 2^-200 -> 0
// implements the causal mask).
__device__ __forceinline__ float fexp2(float x){
#if __has_builtin(__builtin_amdgcn_exp2f)
  return __builtin_amdgcn_exp2f(x);
#else
  float r; asm("v_exp_f32 %0, %1\n\ts_nop 0" : "=v"(r) : "v"(x)); return r;
#endif
}
__device__ __forceinline__ float frcp(float x){
#if __has_builtin(__builtin_amdgcn_rcpf)
  return __builtin_amdgcn_rcpf(x);
#else
  float r; asm("v_rcp_f32 %0, %1\n\ts_nop 0" : "=v"(r) : "v"(x)); return r;
#endif
}

// ---------------- pos-enc add: xb = bf16(x + pe) ----------------
__global__ __launch_bounds__(256) void posenc_add(
    const float* __restrict__ x, u16* __restrict__ xb)
{
  const int t = blockIdx.x;          // token row 0..4095
  const int s = t & 2047;            // seq position
  const size_t base = (size_t)t * DM;
#pragma unroll
  for (int i = 0; i < 4; ++i){
    const int d = threadIdx.x + i * 256;
    const float e = (float)(d & ~1) * (1.0f / (float)DM);
    const float denom = powf(1000.0f, e);
    const float mat = (float)s / denom;
    const float pe = (d & 1) ? cosf(mat) : sinf(mat);
    xb[base + d] = f2bf(x[base + d] + pe);
  }
}

// ---------- weight transpose+cast v2: 64x64 f32 tiles, float4 loads ----------
// WT layout per layer: [0]=WqT [1]=WkT [2]=WvT [3]=WoT [4]=W1T [5]=W2T
// bid = (l-l0)*1536 + mm*256 + t   (256 tiles of 64x64 per 1024^2 matrix)
__global__ __launch_bounds__(256) void transpose6(
    const float* __restrict__ Wq, const float* __restrict__ Wk, const float* __restrict__ Wv,
    const float* __restrict__ Wo, const float* __restrict__ W1, const float* __restrict__ W2,
    u16* __restrict__ WT, int l0)
{
  __shared__ float tile[64 * 65];          // tile[c*65 + r] = src[tk+r][tn+c]
  const int bid = blockIdx.x;
  const int l   = l0 + bid / 1536;
  const int rem = bid % 1536;
  const int mm  = rem >> 8;                // matrix 0..5
  const int t   = rem & 255;
  const int tn  = (t & 15) * 64;           // src col block (= dst row block)
  const int tk  = (t >> 4) * 64;           // src row block (= dst col block)
  const float* src = (mm==0)?Wq:(mm==1)?Wk:(mm==2)?Wv:(mm==3)?Wo:(mm==4)?W1:W2;
  src += (size_t)l * 1048576;
  u16* dst = WT + ((size_t)(l - l0) * 6 + mm) * 1048576;
  const int tx = threadIdx.x & 15, ty = threadIdx.x >> 4;   // tx 0..15, ty 0..15
#pragma unroll
  for (int r = 0; r < 4; ++r){
    const int row = ty + 16 * r;
    const float4 v = *(const float4*)(src + (size_t)(tk + row) * 1024 + tn + 4 * tx);
    tile[(4*tx + 0) * 65 + row] = v.x;     // transposed scatter (<=2-way banks)
    tile[(4*tx + 1) * 65 + row] = v.y;
    tile[(4*tx + 2) * 65 + row] = v.z;
    tile[(4*tx + 3) * 65 + row] = v.w;
  }
  __syncthreads();
#pragma unroll
  for (int r = 0; r < 4; ++r){
    const int nrow = ty + 16 * r;          // dst row (src col)
    ushort4 o;
    o.x = f2bf(tile[nrow * 65 + 4*tx + 0]);
    o.y = f2bf(tile[nrow * 65 + 4*tx + 1]);
    o.z = f2bf(tile[nrow * 65 + 4*tx + 2]);
    o.w = f2bf(tile[nrow * 65 + 4*tx + 3]);
    *(ushort4*)(dst + (size_t)(tn + nrow) * 1024 + tk + 4 * tx) = o;
  }
}

#define BK 64
#define KD 1024

// ---------------- qkv GEMM, 8-phase schedule (T3+T4+T5) ----------------
// C[4096][3072] = xb @ [WqT|WkT|WvT]^T, bias, q*=0.125 -> bf16.
// BM=256 x BN=192, 512 thr (8 waves, 2M x 4N), per-wave 128x48 (acc[8][3]).
// Grid 256 = 1 block/CU. LDS 2 x 56KB. 4 phases/K-tile of 12 MFMA; prefetch
// spread 2/2/2/1 across phases; vmcnt(0) ONCE per K-tile (loads 1 iter old).
#define QBM 256
#define QBN 192
#define QNT (KD/BK)   // 16

__global__ __launch_bounds__(512, 2) void qkv_gemm8(
    const u16* __restrict__ A, const u16* __restrict__ BT,
    const float* __restrict__ bq, const float* __restrict__ bk, const float* __restrict__ bvp,
    u16* __restrict__ outB)
{
  __shared__ __align__(16) u16 lds[2][(QBM + QBN) * BK];   // 2 x 57344 B
  const int tid  = threadIdx.x;
  const int lane = tid & 63;
  const int wave = tid >> 6;                  // 0..7
  const int nwg  = gridDim.x;                 // 256
  const int wg   = (blockIdx.x & 7) * (nwg >> 3) + (blockIdx.x >> 3);
  const int nbn  = 3072 / QBN;                // 16
  const size_t m0 = (size_t)(wg / nbn) * QBM;
  const size_t n0 = (size_t)(wg % nbn) * QBN;

  const int srow  = lane >> 3;
  const int sslot = (lane & 7) ^ srow;
  const u16* gA = A  + (m0 + wave*32 + srow) * KD + sslot * 8;  // 4 chunks/wave
  const u16* gB = BT + (n0 + wave*24 + srow) * KD + sslot * 8;  // 3 chunks/wave
  const int loA = wave * 32 * 64;
  const int loB = QBM * BK + wave * 24 * 64;

  auto stage1 = [&](int kt, int buf, int i){  // i: 0..3 = A chunk, 4..6 = B chunk
    const int k0 = kt * BK;
    if (i < 4)
      __builtin_amdgcn_global_load_lds(
          (const __attribute__((address_space(1))) void*)(gA + i*8*KD + k0),
          (__attribute__((address_space(3))) void*)(&lds[buf][loA + i*512]), 16, 0, 0);
    else
      __builtin_amdgcn_global_load_lds(
          (const __attribute__((address_space(1))) void*)(gB + (i-4)*8*KD + k0),
          (__attribute__((address_space(3))) void*)(&lds[buf][loB + (i-4)*512]), 16, 0, 0);
  };

  const int wr = wave >> 2;                   // 0..1 -> rows wr*128
  const int wc = wave & 3;                    // 0..3 -> cols wc*48
  f32x4 acc[8][3] = {};
  short8 bfv[3][2];

#pragma unroll
  for (int i = 0; i < 7; ++i) stage1(0, 0, i);

  for (int kt = 0; kt < QNT; ++kt){
    const int cur = kt & 1;
    asm volatile("s_waitcnt vmcnt(0)" ::: "memory");
    __builtin_amdgcn_sched_barrier(0);
    __builtin_amdgcn_s_barrier();
    const u16* sA = &lds[cur][0];
    const u16* sB = &lds[cur][QBM * BK];
#pragma unroll
    for (int p = 0; p < 4; ++p){
      short8 af[2][2];
#pragma unroll
      for (int i = 0; i < 2; ++i)
#pragma unroll
        for (int kh = 0; kh < 2; ++kh){
          const int ar = wr*128 + (p*2 + i)*16 + (lane & 15);
          af[i][kh] = *(const short8*)(sA + ar*64 + ((((kh<<2)|(lane>>4)) ^ (ar & 7)) * 8));
        }
      if (p == 0){
#pragma unroll
        for (int j = 0; j < 3; ++j)
#pragma unroll
          for (int kh = 0; kh < 2; ++kh){
            const int br = wc*48 + j*16 + (lane & 15);
            bfv[j][kh] = *(const short8*)(sB + br*64 + ((((kh<<2)|(lane>>4)) ^ (br & 7)) * 8));
          }
      }
      if (kt + 1 < QNT){
        stage1(kt + 1, cur ^ 1, p*2);
        if (p*2 + 1 < 7) stage1(kt + 1, cur ^ 1, p*2 + 1);
      }
      __builtin_amdgcn_s_barrier();
      asm volatile("s_waitcnt lgkmcnt(0)" ::: "memory");
      __builtin_amdgcn_sched_barrier(0);
      __builtin_amdgcn_s_setprio(1);
#pragma unroll
      for (int i = 0; i < 2; ++i)
#pragma unroll
        for (int j = 0; j < 3; ++j)
#pragma unroll
          for (int kh = 0; kh < 2; ++kh)
            acc[p*2 + i][j] = __builtin_amdgcn_mfma_f32_16x16x32_bf16(
                af[i][kh], bfv[j][kh], acc[p*2 + i][j], 0, 0, 0);
      __builtin_amdgcn_s_setprio(0);
      __builtin_amdgcn_s_barrier();
    }
  }

#pragma unroll
  for (int m = 0; m < 8; ++m){
    const int growb = wr*128 + m*16 + (lane >> 4) * 4;
#pragma unroll
    for (int j = 0; j < 3; ++j){
      const size_t gcol = n0 + wc*48 + j*16 + (lane & 15);
      float bias;
      if (gcol < 1024)      bias = bq[gcol];
      else if (gcol < 2048) bias = bk[gcol - 1024];
      else                  bias = bvp[gcol - 2048];
#pragma unroll
      for (int r = 0; r < 4; ++r){
        const size_t grow = m0 + growb + r;
        float v = acc[m][j][r] + bias;
        if (gcol < 1024) v *= 0.125f;
        outB[grow * 3072 + gcol] = f2bf(v);
      }
    }
  }
}

// ---------------- N=1024 GEMM, 8-phase-style (2 meaty phases/K-tile) ----------------
// C[4096][1024] = A @ BT^T (+bias / relu) -> bf16.
// BM=256 x BN=64, 512 thr (8 waves, 4M x 2N), per-wave 64x32 (acc[4][2]).
// Grid 16x16=256 = 1 block/CU. LDS 2 x 40KB. 2 phases/K-tile of 8 MFMA;
// prefetch 5 chunks/wave spread 3+2; vmcnt(0) once per K-tile.
#define SBM 256
#define SBN 64

template<int MODE>   // 0: +bias ; 1: relu(+bias)
__global__ __launch_bounds__(512, 2) void gemm8_n1024(
    const u16* __restrict__ A, const u16* __restrict__ BT,
    const float* __restrict__ bias0, u16* __restrict__ outB)
{
  __shared__ __align__(16) u16 lds[2][(SBM + SBN) * BK];   // 2 x 40960 B
  const int tid  = threadIdx.x;
  const int lane = tid & 63;
  const int wave = tid >> 6;                  // 0..7
  const int nwg  = gridDim.x;                 // 256
  const int wg   = (blockIdx.x & 7) * (nwg >> 3) + (blockIdx.x >> 3);
  const size_t m0 = (size_t)(wg >> 4) * SBM;  // 16 n-blocks
  const size_t n0 = (size_t)(wg & 15) * SBN;

  const int srow  = lane >> 3;
  const int sslot = (lane & 7) ^ srow;
  const u16* gA = A  + (m0 + wave*32 + srow) * KD + sslot * 8;  // 4 chunks/wave
  const u16* gB = BT + (n0 + wave*8  + srow) * KD + sslot * 8;  // 1 chunk/wave
  const int loA = wave * 32 * 64;
  const int loB = SBM * BK + wave * 8 * 64;

  auto stage1 = [&](int kt, int buf, int i){  // i: 0..3 = A chunk, 4 = B chunk
    const int k0 = kt * BK;
    if (i < 4)
      __builtin_amdgcn_global_load_lds(
          (const __attribute__((address_space(1))) void*)(gA + i*8*KD + k0),
          (__attribute__((address_space(3))) void*)(&lds[buf][loA + i*512]), 16, 0, 0);
    else
      __builtin_amdgcn_global_load_lds(
          (const __attribute__((address_space(1))) void*)(gB + k0),
          (__attribute__((address_space(3))) void*)(&lds[buf][loB]), 16, 0, 0);
  };

  const int wr = wave >> 1;                   // 0..3 -> rows wr*64
  const int wc = wave & 1;                    // 0..1 -> cols wc*32
  f32x4 acc[4][2] = {};
  short8 bfv[2][2];

#pragma unroll
  for (int i = 0; i < 5; ++i) stage1(0, 0, i);

  for (int kt = 0; kt < KD/BK; ++kt){
    const int cur = kt & 1;
    asm volatile("s_waitcnt vmcnt(0)" ::: "memory");
    __builtin_amdgcn_sched_barrier(0);
    __builtin_amdgcn_s_barrier();
    const u16* sA = &lds[cur][0];
    const u16* sB = &lds[cur][SBM * BK];
#pragma unroll
    for (int p = 0; p < 2; ++p){
      short8 af[2][2];
#pragma unroll
      for (int i = 0; i < 2; ++i)
#pragma unroll
        for (int kh = 0; kh < 2; ++kh){
          const int ar = wr*64 + (p*2 + i)*16 + (lane & 15);
          af[i][kh] = *(const short8*)(sA + ar*64 + ((((kh<<2)|(lane>>4)) ^ (ar & 7)) * 8));
        }
      if (p == 0){
#pragma unroll
        for (int j = 0; j < 2; ++j)
#pragma unroll
          for (int kh = 0; kh < 2; ++kh){
            const int br = wc*32 + j*16 + (lane & 15);
            bfv[j][kh] = *(const short8*)(sB + br*64 + ((((kh<<2)|(lane>>4)) ^ (br & 7)) * 8));
          }
      }
      if (kt + 1 < KD/BK){                     // spread 5 chunks: 3 + 2
        stage1(kt + 1, cur ^ 1, p*3);
        stage1(kt + 1, cur ^ 1, p*3 + 1);
        if (p == 0) stage1(kt + 1, cur ^ 1, 2);
      }
      __builtin_amdgcn_s_barrier();
      asm volatile("s_waitcnt lgkmcnt(0)" ::: "memory");
      __builtin_amdgcn_sched_barrier(0);
      __builtin_amdgcn_s_setprio(1);
#pragma unroll
      for (int i = 0; i < 2; ++i)
#pragma unroll
        for (int j = 0; j < 2; ++j)
#pragma unroll
          for (int kh = 0; kh < 2; ++kh)
            acc[p*2 + i][j] = __builtin_amdgcn_mfma_f32_16x16x32_bf16(
                af[i][kh], bfv[j][kh], acc[p*2 + i][j], 0, 0, 0);
      __builtin_amdgcn_s_setprio(0);
      __builtin_amdgcn_s_barrier();
    }
  }

#pragma unroll
  for (int m = 0; m < 4; ++m){
    const int growb = wr*64 + m*16 + (lane >> 4) * 4;
#pragma unroll
    for (int j = 0; j < 2; ++j){
      const size_t gcol = n0 + wc*32 + j*16 + (lane & 15);
      const float bv = bias0[gcol];
#pragma unroll
      for (int r = 0; r < 4; ++r){
        const size_t grow = m0 + growb + r;
        float v = acc[m][j][r] + bv;
        if constexpr (MODE == 1) v = fmaxf(v, 0.0f);
        outB[grow * 1024 + gcol] = f2bf(v);
      }
    }
  }
}

// ---------------- per-token channel attention (2 pairs/wave, 4 waves/block) ----------------
__global__ __launch_bounds__(256) void attn_chan(
    const u16* __restrict__ qkv, u16* __restrict__ av)
{
  __shared__ __align__(16) float2 skv[4][2][64];
  const int t    = blockIdx.x >> 1;
  const int lane = threadIdx.x & 63;
  const int wave = threadIdx.x >> 6;
  const int h0   = (blockIdx.x & 1) * 8 + wave * 2;
  const int r3   = lane & 3;
  const size_t base = (size_t)t * 3072 + h0 * 64 + lane;
  const float q0 = bf2f(qkv[base])      * 1.44269504f;
  const float q1 = bf2f(qkv[base + 64]) * 1.44269504f;
  skv[wave][0][lane] = make_float2(bf2f(qkv[base + 1024]), bf2f(qkv[base + 2048]));
  skv[wave][1][lane] = make_float2(bf2f(qkv[base + 1088]), bf2f(qkv[base + 2112]));
  const float2* kwa = skv[wave][0];
  const float2* kwb = skv[wave][1];
  float sa0=0.f, sa1=0.f, aa0=0.f, aa1=0.f;
  float sb0=0.f, sb1=0.f, ab0=0.f, ab1=0.f;
#pragma unroll
  for (int j0 = 0; j0 < 64; j0 += 4){
    const float4 A0 = *(const float4*)(kwa + j0);
    const float4 A1 = *(const float4*)(kwa + j0 + 2);
    const float4 B0 = *(const float4*)(kwb + j0);
    const float4 B1 = *(const float4*)(kwb + j0 + 2);
    const float bias = (j0 + 3 <= lane) ? 0.0f : -200.0f;
    const float ea0 = fexp2(fmaf(q0, A0.x, bias));
    const float ea1 = fexp2(fmaf(q0, A0.z, bias));
    const float ea2 = fexp2(fmaf(q0, A1.x, bias));
    const float ea3 = fexp2(fmaf(q0, A1.z, bias));
    const float eb0 = fexp2(fmaf(q1, B0.x, bias));
    const float eb1 = fexp2(fmaf(q1, B0.z, bias));
    const float eb2 = fexp2(fmaf(q1, B1.x, bias));
    const float eb3 = fexp2(fmaf(q1, B1.z, bias));
    sa0 += ea0 + ea2;  sa1 += ea1 + ea3;
    sb0 += eb0 + eb2;  sb1 += eb1 + eb3;
    aa0 = fmaf(ea0, A0.y, fmaf(ea2, A1.y, aa0));
    aa1 = fmaf(ea1, A0.w, fmaf(ea3, A1.w, aa1));
    ab0 = fmaf(eb0, B0.y, fmaf(eb2, B1.y, ab0));
    ab1 = fmaf(eb1, B0.w, fmaf(eb3, B1.w, ab1));
  }
#pragma unroll
  for (int s = 0; s < 3; ++s){
    const int jj = lane - r3 + s;
    const float bias = (s <= r3 && r3 < 3) ? 0.0f : -200.0f;
    const float2 ka = kwa[jj];
    const float2 kb = kwb[jj];
    const float ea = fexp2(fmaf(q0, ka.x, bias));
    const float eb = fexp2(fmaf(q1, kb.x, bias));
    sa0 += ea; aa0 = fmaf(ea, ka.y, aa0);
    sb0 += eb; ab0 = fmaf(eb, kb.y, ab0);
  }
  av[(size_t)t * DM + h0*64 + lane]      = f2bf((aa0 + aa1) * frcp(sa0 + sa1));
  av[(size_t)t * DM + h0*64 + 64 + lane] = f2bf((ab0 + ab1) * frcp(sb0 + sb1));
}

// ---------------- residual add + LayerNorm: ONE ROW PER WAVE, barrier-free ----------------
__global__ __launch_bounds__(256) void residual_ln(
    const u16* __restrict__ y, const u16* xres,
    const float* __restrict__ gamma, const float* __restrict__ beta,
    float* xoutF, u16* xb)
{
  const int lane = threadIdx.x & 63, wave = threadIdx.x >> 6;
  const int row  = blockIdx.x * 4 + wave;
  const ushort4* yr = (const ushort4*)(y    + (size_t)row*DM);
  const ushort4* xr = (const ushort4*)(xres + (size_t)row*DM);
  float4 s[4];
  float psum = 0.0f;
#pragma unroll
  for (int c = 0; c < 4; ++c){
    const int idx = c*64 + lane;
    const ushort4 a = yr[idx];
    const ushort4 b = xr[idx];
    s[c].x = bf2f(a.x)+bf2f(b.x); s[c].y = bf2f(a.y)+bf2f(b.y);
    s[c].z = bf2f(a.z)+bf2f(b.z); s[c].w = bf2f(a.w)+bf2f(b.w);
    psum += (s[c].x + s[c].y) + (s[c].z + s[c].w);
  }
#pragma unroll
  for (int o = 32; o; o >>= 1) psum += __shfl_xor(psum, o);
  const float mu = psum * (1.0f/(float)DM);
  float q2 = 0.0f;
#pragma unroll
  for (int c = 0; c < 4; ++c){
    s[c].x -= mu; s[c].y -= mu; s[c].z -= mu; s[c].w -= mu;
    q2 += s[c].x*s[c].x + s[c].y*s[c].y + s[c].z*s[c].z + s[c].w*s[c].w;
  }
#pragma unroll
  for (int o = 32; o; o >>= 1) q2 += __shfl_xor(q2, o);
  const float rstd = rsqrtf(q2 * (1.0f/(float)DM) + 1e-5f);
#pragma unroll
  for (int c = 0; c < 4; ++c){
    const int idx = c*64 + lane;
    const float4 g  = ((const float4*)gamma)[idx];
    const float4 be = ((const float4*)beta)[idx];
    float4 o4;
    o4.x = s[c].x*rstd*g.x + be.x;
    o4.y = s[c].y*rstd*g.y + be.y;
    o4.z = s[c].z*rstd*g.z + be.z;
    o4.w = s[c].w*rstd*g.w + be.w;
    if (xoutF) ((float4*)(xoutF + (size_t)row*DM))[idx] = o4;
    ushort4 ob; ob.x=f2bf(o4.x); ob.y=f2bf(o4.y); ob.z=f2bf(o4.z); ob.w=f2bf(o4.w);
    ((ushort4*)(xb + (size_t)row*DM))[idx] = ob;
  }
}

// ---------------------------------------------------------------------------
extern "C" void kernel_launch(void* const* d_in, const int* in_sizes, int n_in,
                              void* d_out, int out_size, void* d_ws, size_t ws_size,
                              hipStream_t stream)
{
  const float* x    = (const float*)d_in[0];
  const float* Wq   = (const float*)d_in[1];
  const float* bq   = (const float*)d_in[2];
  const float* Wk   = (const float*)d_in[3];
  const float* bk   = (const float*)d_in[4];
  const float* Wv   = (const float*)d_in[5];
  const float* bv   = (const float*)d_in[6];
  const float* Wo   = (const float*)d_in[7];
  const float* bo   = (const float*)d_in[8];
  const float* W1   = (const float*)d_in[9];
  const float* b1   = (const float*)d_in[10];
  const float* W2   = (const float*)d_in[11];
  const float* b2   = (const float*)d_in[12];
  const float* gam  = (const float*)d_in[13];
  const float* bet  = (const float*)d_in[14];

  char* ws = (char*)d_ws;
  size_t off = 0;
  auto alloc = [&](size_t b){ void* p = ws + off; off = (off + b + 255) & ~(size_t)255; return p; };

  const size_t oneWT = 6ull*1048576*2;
  const size_t rest  = ((size_t)TOK*DM*2)   // xb
                     + ((size_t)TOK*3072*2) // qkv
                     + ((size_t)TOK*DM*2)   // avb
                     + ((size_t)TOK*DM*2)   // hbuf
                     + ((size_t)TOK*DM*2)   // ybuf
                     + 4096;
  const bool all4 = (4*oneWT + rest) <= ws_size;

  u16*   WT   = (u16*)  alloc(all4 ? 4*oneWT : oneWT);
  u16*   xb   = (u16*)  alloc((size_t)TOK*DM*2);
  u16*   qkv  = (u16*)  alloc((size_t)TOK*3072*2);
  u16*   avb  = (u16*)  alloc((size_t)TOK*DM*2);
  u16*   hbuf = (u16*)  alloc((size_t)TOK*DM*2);
  u16*   ybuf = (u16*)  alloc((size_t)TOK*DM*2);
  if (off > ws_size) return;  // insufficient scratch -> fail loudly (poisoned d_out)

  posenc_add<<<TOK, 256, 0, stream>>>(x, xb);
  if (all4)
    transpose6<<<4*1536, 256, 0, stream>>>(Wq, Wk, Wv, Wo, W1, W2, WT, 0);

  for (int l = 0; l < 4; ++l){
    u16* wt = all4 ? (WT + (size_t)l * 6 * 1048576) : WT;
    if (!all4)
      transpose6<<<1536, 256, 0, stream>>>(Wq, Wk, Wv, Wo, W1, W2, WT, l);
    // q,k,v = x@W{q,k,v}+b (q pre-scaled by 1/8)  [8-phase, grid 256 = 1 block/CU]
    qkv_gemm8<<<(TOK/QBM)*(3072/QBN), 512, 0, stream>>>(
        xb, wt, bq + l*1024, bk + l*1024, bv + l*1024, qkv);
    // channel attention  [grid 8192 x 256 thr]
    attn_chan<<<TOK*2, 256, 0, stream>>>(qkv, avb);
    // attn_out = av@Wo+bo -> bf16  [8-phase-style, grid 256]
    gemm8_n1024<0><<<(TOK/SBM)*(1024/SBN), 512, 0, stream>>>(
        avb, wt + 3ull*1048576, bo + l*1024, ybuf);
    residual_ln<<<TOK/4, 256, 0, stream>>>(ybuf, xb, gam + l*1024, bet + l*1024, nullptr, xb);
    // h = relu(x@W1+b1) -> bf16
    gemm8_n1024<1><<<(TOK/SBM)*(1024/SBN), 512, 0, stream>>>(
        xb, wt + 4ull*1048576, b1 + l*1024, hbuf);
    // y = h@W2+b2 -> bf16
    gemm8_n1024<0><<<(TOK/SBM)*(1024/SBN), 512, 0, stream>>>(
        hbuf, wt + 5ull*1048576, b2 + l*1024, ybuf);
    residual_ln<<<TOK/4, 256, 0, stream>>>(ybuf, xb, gam + l*1024, bet + l*1024,
                                           (l == 3) ? (float*)d_out : nullptr, xb);
  }
}

// Round 19
// 536.203 us; speedup vs baseline: 1.0556x; 1.0556x over previous
//
#include <hip/hip_runtime.h>
#include <hip/hip_bf16.h>
#include <stdint.h>

// Encoder: B=2,S=2048,D=1024,HID=1024,NH=16,C=64,L=4. 4096 token-rows.
#define TOK 4096
#define DM  1024

using u16 = unsigned short;
typedef __attribute__((ext_vector_type(8))) short short8;   // bf16x8 frag (4 VGPR)
typedef __attribute__((ext_vector_type(4))) float f32x4;

__device__ __forceinline__ u16 f2bf(float f){
  unsigned u = __float_as_uint(f);
  return (u16)((u + 0x7fffu + ((u >> 16) & 1u)) >> 16);   // RNE
}
__device__ __forceinline__ float bf2f(u16 h){ return __uint_as_float(((unsigned)h) << 16); }

// raw hardware exp2 / rcp (skip OCML guards; args range-safe; 2^-200 -> 0
// implements the causal mask).
__device__ __forceinline__ float fexp2(float x){
#if __has_builtin(__builtin_amdgcn_exp2f)
  return __builtin_amdgcn_exp2f(x);
#else
  float r; asm("v_exp_f32 %0, %1\n\ts_nop 0" : "=v"(r) : "v"(x)); return r;
#endif
}
__device__ __forceinline__ float frcp(float x){
#if __has_builtin(__builtin_amdgcn_rcpf)
  return __builtin_amdgcn_rcpf(x);
#else
  float r; asm("v_rcp_f32 %0, %1\n\ts_nop 0" : "=v"(r) : "v"(x)); return r;
#endif
}

// ---------------- pos-enc add: xb = bf16(x + pe) ----------------
__global__ __launch_bounds__(256) void posenc_add(
    const float* __restrict__ x, u16* __restrict__ xb)
{
  const int t = blockIdx.x;          // token row 0..4095
  const int s = t & 2047;            // seq position
  const size_t base = (size_t)t * DM;
#pragma unroll
  for (int i = 0; i < 4; ++i){
    const int d = threadIdx.x + i * 256;
    const float e = (float)(d & ~1) * (1.0f / (float)DM);
    const float denom = powf(1000.0f, e);
    const float mat = (float)s / denom;
    const float pe = (d & 1) ? cosf(mat) : sinf(mat);
    xb[base + d] = f2bf(x[base + d] + pe);
  }
}

// ---------- weight transpose+cast v2: 64x64 f32 tiles, float4 loads ----------
// WT layout per layer: [0]=WqT [1]=WkT [2]=WvT [3]=WoT [4]=W1T [5]=W2T
// bid = (l-l0)*1536 + mm*256 + t   (256 tiles of 64x64 per 1024^2 matrix)
__global__ __launch_bounds__(256) void transpose6(
    const float* __restrict__ Wq, const float* __restrict__ Wk, const float* __restrict__ Wv,
    const float* __restrict__ Wo, const float* __restrict__ W1, const float* __restrict__ W2,
    u16* __restrict__ WT, int l0)
{
  __shared__ float tile[64 * 65];          // tile[c*65 + r] = src[tk+r][tn+c]
  const int bid = blockIdx.x;
  const int l   = l0 + bid / 1536;
  const int rem = bid % 1536;
  const int mm  = rem >> 8;                // matrix 0..5
  const int t   = rem & 255;
  const int tn  = (t & 15) * 64;           // src col block (= dst row block)
  const int tk  = (t >> 4) * 64;           // src row block (= dst col block)
  const float* src = (mm==0)?Wq:(mm==1)?Wk:(mm==2)?Wv:(mm==3)?Wo:(mm==4)?W1:W2;
  src += (size_t)l * 1048576;
  u16* dst = WT + ((size_t)(l - l0) * 6 + mm) * 1048576;
  const int tx = threadIdx.x & 15, ty = threadIdx.x >> 4;   // tx 0..15, ty 0..15
#pragma unroll
  for (int r = 0; r < 4; ++r){
    const int row = ty + 16 * r;
    const float4 v = *(const float4*)(src + (size_t)(tk + row) * 1024 + tn + 4 * tx);
    tile[(4*tx + 0) * 65 + row] = v.x;     // transposed scatter (<=2-way banks)
    tile[(4*tx + 1) * 65 + row] = v.y;
    tile[(4*tx + 2) * 65 + row] = v.z;
    tile[(4*tx + 3) * 65 + row] = v.w;
  }
  __syncthreads();
#pragma unroll
  for (int r = 0; r < 4; ++r){
    const int nrow = ty + 16 * r;          // dst row (src col)
    ushort4 o;
    o.x = f2bf(tile[nrow * 65 + 4*tx + 0]);
    o.y = f2bf(tile[nrow * 65 + 4*tx + 1]);
    o.z = f2bf(tile[nrow * 65 + 4*tx + 2]);
    o.w = f2bf(tile[nrow * 65 + 4*tx + 3]);
    *(ushort4*)(dst + (size_t)(tn + nrow) * 1024 + tk + 4 * tx) = o;
  }
}

#define BM 128
#define BK 64
#define KD 1024

// ---------------- qkv GEMM, 8-phase schedule (T3+T4+T5) ----------------
// C[4096][3072] = xb @ [WqT|WkT|WvT]^T, bias, q*=0.125 -> bf16.
// BM=256 x BN=192, 512 thr (8 waves, 2M x 4N), per-wave 128x48 (acc[8][3]).
// Grid 256 = 1 block/CU. LDS 2 x 56KB. 4 phases/K-tile of 12 MFMA; prefetch
// spread 2/2/2/1 across phases; vmcnt(0) ONCE per K-tile (loads 1 iter old).
// [r17: qkv 38 -> ~33 us. 8-phase pays at THIS shape only; N=1024 port
//  regressed (r18: thin 8-MFMA phases, barrier-dominated) and was reverted.]
#define QBM 256
#define QBN 192
#define QNT (KD/BK)   // 16

__global__ __launch_bounds__(512, 2) void qkv_gemm8(
    const u16* __restrict__ A, const u16* __restrict__ BT,
    const float* __restrict__ bq, const float* __restrict__ bk, const float* __restrict__ bvp,
    u16* __restrict__ outB)
{
  __shared__ __align__(16) u16 lds[2][(QBM + QBN) * BK];   // 2 x 57344 B
  const int tid  = threadIdx.x;
  const int lane = tid & 63;
  const int wave = tid >> 6;                  // 0..7
  const int nwg  = gridDim.x;                 // 256
  const int wg   = (blockIdx.x & 7) * (nwg >> 3) + (blockIdx.x >> 3);
  const int nbn  = 3072 / QBN;                // 16
  const size_t m0 = (size_t)(wg / nbn) * QBM;
  const size_t n0 = (size_t)(wg % nbn) * QBN;

  const int srow  = lane >> 3;
  const int sslot = (lane & 7) ^ srow;
  const u16* gA = A  + (m0 + wave*32 + srow) * KD + sslot * 8;  // 4 chunks/wave
  const u16* gB = BT + (n0 + wave*24 + srow) * KD + sslot * 8;  // 3 chunks/wave
  const int loA = wave * 32 * 64;
  const int loB = QBM * BK + wave * 24 * 64;

  auto stage1 = [&](int kt, int buf, int i){  // i: 0..3 = A chunk, 4..6 = B chunk
    const int k0 = kt * BK;
    if (i < 4)
      __builtin_amdgcn_global_load_lds(
          (const __attribute__((address_space(1))) void*)(gA + i*8*KD + k0),
          (__attribute__((address_space(3))) void*)(&lds[buf][loA + i*512]), 16, 0, 0);
    else
      __builtin_amdgcn_global_load_lds(
          (const __attribute__((address_space(1))) void*)(gB + (i-4)*8*KD + k0),
          (__attribute__((address_space(3))) void*)(&lds[buf][loB + (i-4)*512]), 16, 0, 0);
  };

  const int wr = wave >> 2;                   // 0..1 -> rows wr*128
  const int wc = wave & 3;                    // 0..3 -> cols wc*48
  f32x4 acc[8][3] = {};
  short8 bfv[3][2];

#pragma unroll
  for (int i = 0; i < 7; ++i) stage1(0, 0, i);

  for (int kt = 0; kt < QNT; ++kt){
    const int cur = kt & 1;
    asm volatile("s_waitcnt vmcnt(0)" ::: "memory");
    __builtin_amdgcn_sched_barrier(0);
    __builtin_amdgcn_s_barrier();
    const u16* sA = &lds[cur][0];
    const u16* sB = &lds[cur][QBM * BK];
#pragma unroll
    for (int p = 0; p < 4; ++p){
      short8 af[2][2];
#pragma unroll
      for (int i = 0; i < 2; ++i)
#pragma unroll
        for (int kh = 0; kh < 2; ++kh){
          const int ar = wr*128 + (p*2 + i)*16 + (lane & 15);
          af[i][kh] = *(const short8*)(sA + ar*64 + ((((kh<<2)|(lane>>4)) ^ (ar & 7)) * 8));
        }
      if (p == 0){
#pragma unroll
        for (int j = 0; j < 3; ++j)
#pragma unroll
          for (int kh = 0; kh < 2; ++kh){
            const int br = wc*48 + j*16 + (lane & 15);
            bfv[j][kh] = *(const short8*)(sB + br*64 + ((((kh<<2)|(lane>>4)) ^ (br & 7)) * 8));
          }
      }
      if (kt + 1 < QNT){
        stage1(kt + 1, cur ^ 1, p*2);
        if (p*2 + 1 < 7) stage1(kt + 1, cur ^ 1, p*2 + 1);
      }
      __builtin_amdgcn_s_barrier();
      asm volatile("s_waitcnt lgkmcnt(0)" ::: "memory");
      __builtin_amdgcn_sched_barrier(0);
      __builtin_amdgcn_s_setprio(1);
#pragma unroll
      for (int i = 0; i < 2; ++i)
#pragma unroll
        for (int j = 0; j < 3; ++j)
#pragma unroll
          for (int kh = 0; kh < 2; ++kh)
            acc[p*2 + i][j] = __builtin_amdgcn_mfma_f32_16x16x32_bf16(
                af[i][kh], bfv[j][kh], acc[p*2 + i][j], 0, 0, 0);
      __builtin_amdgcn_s_setprio(0);
      __builtin_amdgcn_s_barrier();
    }
  }

#pragma unroll
  for (int m = 0; m < 8; ++m){
    const int growb = wr*128 + m*16 + (lane >> 4) * 4;
#pragma unroll
    for (int j = 0; j < 3; ++j){
      const size_t gcol = n0 + wc*48 + j*16 + (lane & 15);
      float bias;
      if (gcol < 1024)      bias = bq[gcol];
      else if (gcol < 2048) bias = bk[gcol - 1024];
      else                  bias = bvp[gcol - 2048];
#pragma unroll
      for (int r = 0; r < 4; ++r){
        const size_t grow = m0 + growb + r;
        float v = acc[m][j][r] + bias;
        if (gcol < 1024) v *= 0.125f;
        outB[grow * 3072 + gcol] = f2bf(v);
      }
    }
  }
}

// ---------------- bf16 MFMA GEMM: C[M][N] = A[M][1024] @ BT[N][1024]^T ----------------
// 128x64 tile, BK=64, dbuf LDS, issue-early prefetch + single __syncthreads
// (r10 schedule -- best measured for this shape; 8-phase port regressed, reverted).
// MODE 0: +bias -> bf16 ; MODE 1: relu(+bias) -> bf16
template<int MODE>
__global__ __launch_bounds__(256, 3) void gemm_k1024(
    const u16* __restrict__ A, const u16* __restrict__ BT,
    const float* __restrict__ bias0,
    u16* __restrict__ outB, int M, int N)
{
  constexpr int BNt = 64;
  constexpr int NFR = 2;
  __shared__ __align__(16) u16 lds2[2][(BM + BNt) * BK];   // 2 x 24KB
  const int tid  = threadIdx.x;
  const int lane = tid & 63;
  const int wave = tid >> 6;
  const int nbn = N / BNt;
  const int nwg = gridDim.x;
  const int wg  = (blockIdx.x & 7) * (nwg >> 3) + (blockIdx.x >> 3);
  const size_t m0 = (size_t)(wg / nbn) * BM;
  const size_t n0 = (size_t)(wg % nbn) * BNt;

  const int srow  = lane >> 3;
  const int sslot = (lane & 7) ^ srow;
  const u16* gA = A  + (m0 + wave*32 + srow) * KD + sslot * 8;
  const u16* gB = BT + (n0 + wave*16 + srow) * KD + sslot * 8;
  const int loA = (wave*32) * 64;
  const int loB = BM*BK + (wave*16) * 64;

  const int wm = (wave >> 1) * 64;
  const int wn = (wave & 1) * 32;
  f32x4 acc[4][NFR] = {};

  auto stage = [&](int kt, int buf){
    u16* base = lds2[buf];
    const int k0 = kt * BK;
#pragma unroll
    for (int p = 0; p < 4; ++p)
      __builtin_amdgcn_global_load_lds(
          (const __attribute__((address_space(1))) void*)(gA + p*8*KD + k0),
          (__attribute__((address_space(3))) void*)(base + loA + p*512), 16, 0, 0);
#pragma unroll
    for (int p = 0; p < 2; ++p)
      __builtin_amdgcn_global_load_lds(
          (const __attribute__((address_space(1))) void*)(gB + p*8*KD + k0),
          (__attribute__((address_space(3))) void*)(base + loB + p*512), 16, 0, 0);
  };
  auto compute = [&](int buf){
    const u16* sAc = lds2[buf];
    const u16* sBc = sAc + BM*BK;
#pragma unroll
    for (int kk = 0; kk < 2; ++kk){
      short8 af[4], bfr[NFR];
      const int kidx = kk*4 + (lane >> 4);
#pragma unroll
      for (int i = 0; i < 4; ++i){
        const int arow = wm + i*16 + (lane & 15);
        af[i]  = *(const short8*)(sAc + arow*64 + (kidx ^ (arow & 7)) * 8);
      }
#pragma unroll
      for (int j = 0; j < NFR; ++j){
        const int brow = wn + j*16 + (lane & 15);
        bfr[j] = *(const short8*)(sBc + brow*64 + (kidx ^ (brow & 7)) * 8);
      }
#pragma unroll
      for (int i = 0; i < 4; ++i)
#pragma unroll
        for (int j = 0; j < NFR; ++j)
          acc[i][j] = __builtin_amdgcn_mfma_f32_16x16x32_bf16(af[i], bfr[j], acc[i][j], 0, 0, 0);
    }
  };

  stage(0, 0);
  __syncthreads();
  for (int kt = 0; kt < KD/BK; ++kt){
    if (kt + 1 < KD/BK) stage(kt + 1, (kt + 1) & 1);
    compute(kt & 1);
    __syncthreads();
  }

#pragma unroll
  for (int i = 0; i < 4; ++i){
    const int growb = wm + i*16 + (lane >> 4) * 4;
#pragma unroll
    for (int j = 0; j < NFR; ++j){
      const size_t gcol = n0 + wn + j*16 + (lane & 15);
      const float bv = bias0[gcol];
#pragma unroll
      for (int r = 0; r < 4; ++r){
        const size_t grow = m0 + growb + r;
        float v = acc[i][j][r] + bv;
        if constexpr (MODE == 1) v = fmaxf(v, 0.0f);
        outB[grow * N + gcol] = f2bf(v);
      }
    }
  }
}

// ---------------- per-token channel attention (2 pairs/wave, 4 waves/block) ----------------
__global__ __launch_bounds__(256) void attn_chan(
    const u16* __restrict__ qkv, u16* __restrict__ av)
{
  __shared__ __align__(16) float2 skv[4][2][64];
  const int t    = blockIdx.x >> 1;
  const int lane = threadIdx.x & 63;
  const int wave = threadIdx.x >> 6;
  const int h0   = (blockIdx.x & 1) * 8 + wave * 2;
  const int r3   = lane & 3;
  const size_t base = (size_t)t * 3072 + h0 * 64 + lane;
  const float q0 = bf2f(qkv[base])      * 1.44269504f;
  const float q1 = bf2f(qkv[base + 64]) * 1.44269504f;
  skv[wave][0][lane] = make_float2(bf2f(qkv[base + 1024]), bf2f(qkv[base + 2048]));
  skv[wave][1][lane] = make_float2(bf2f(qkv[base + 1088]), bf2f(qkv[base + 2112]));
  const float2* kwa = skv[wave][0];
  const float2* kwb = skv[wave][1];
  float sa0=0.f, sa1=0.f, aa0=0.f, aa1=0.f;
  float sb0=0.f, sb1=0.f, ab0=0.f, ab1=0.f;
#pragma unroll
  for (int j0 = 0; j0 < 64; j0 += 4){
    const float4 A0 = *(const float4*)(kwa + j0);
    const float4 A1 = *(const float4*)(kwa + j0 + 2);
    const float4 B0 = *(const float4*)(kwb + j0);
    const float4 B1 = *(const float4*)(kwb + j0 + 2);
    const float bias = (j0 + 3 <= lane) ? 0.0f : -200.0f;
    const float ea0 = fexp2(fmaf(q0, A0.x, bias));
    const float ea1 = fexp2(fmaf(q0, A0.z, bias));
    const float ea2 = fexp2(fmaf(q0, A1.x, bias));
    const float ea3 = fexp2(fmaf(q0, A1.z, bias));
    const float eb0 = fexp2(fmaf(q1, B0.x, bias));
    const float eb1 = fexp2(fmaf(q1, B0.z, bias));
    const float eb2 = fexp2(fmaf(q1, B1.x, bias));
    const float eb3 = fexp2(fmaf(q1, B1.z, bias));
    sa0 += ea0 + ea2;  sa1 += ea1 + ea3;
    sb0 += eb0 + eb2;  sb1 += eb1 + eb3;
    aa0 = fmaf(ea0, A0.y, fmaf(ea2, A1.y, aa0));
    aa1 = fmaf(ea1, A0.w, fmaf(ea3, A1.w, aa1));
    ab0 = fmaf(eb0, B0.y, fmaf(eb2, B1.y, ab0));
    ab1 = fmaf(eb1, B0.w, fmaf(eb3, B1.w, ab1));
  }
#pragma unroll
  for (int s = 0; s < 3; ++s){
    const int jj = lane - r3 + s;
    const float bias = (s <= r3 && r3 < 3) ? 0.0f : -200.0f;
    const float2 ka = kwa[jj];
    const float2 kb = kwb[jj];
    const float ea = fexp2(fmaf(q0, ka.x, bias));
    const float eb = fexp2(fmaf(q1, kb.x, bias));
    sa0 += ea; aa0 = fmaf(ea, ka.y, aa0);
    sb0 += eb; ab0 = fmaf(eb, kb.y, ab0);
  }
  av[(size_t)t * DM + h0*64 + lane]      = f2bf((aa0 + aa1) * frcp(sa0 + sa1));
  av[(size_t)t * DM + h0*64 + 64 + lane] = f2bf((ab0 + ab1) * frcp(sb0 + sb1));
}

// ---------------- residual add + LayerNorm: ONE ROW PER WAVE, barrier-free ----------------
__global__ __launch_bounds__(256) void residual_ln(
    const u16* __restrict__ y, const u16* xres,
    const float* __restrict__ gamma, const float* __restrict__ beta,
    float* xoutF, u16* xb)
{
  const int lane = threadIdx.x & 63, wave = threadIdx.x >> 6;
  const int row  = blockIdx.x * 4 + wave;
  const ushort4* yr = (const ushort4*)(y    + (size_t)row*DM);
  const ushort4* xr = (const ushort4*)(xres + (size_t)row*DM);
  float4 s[4];
  float psum = 0.0f;
#pragma unroll
  for (int c = 0; c < 4; ++c){
    const int idx = c*64 + lane;
    const ushort4 a = yr[idx];
    const ushort4 b = xr[idx];
    s[c].x = bf2f(a.x)+bf2f(b.x); s[c].y = bf2f(a.y)+bf2f(b.y);
    s[c].z = bf2f(a.z)+bf2f(b.z); s[c].w = bf2f(a.w)+bf2f(b.w);
    psum += (s[c].x + s[c].y) + (s[c].z + s[c].w);
  }
#pragma unroll
  for (int o = 32; o; o >>= 1) psum += __shfl_xor(psum, o);
  const float mu = psum * (1.0f/(float)DM);
  float q2 = 0.0f;
#pragma unroll
  for (int c = 0; c < 4; ++c){
    s[c].x -= mu; s[c].y -= mu; s[c].z -= mu; s[c].w -= mu;
    q2 += s[c].x*s[c].x + s[c].y*s[c].y + s[c].z*s[c].z + s[c].w*s[c].w;
  }
#pragma unroll
  for (int o = 32; o; o >>= 1) q2 += __shfl_xor(q2, o);
  const float rstd = rsqrtf(q2 * (1.0f/(float)DM) + 1e-5f);
#pragma unroll
  for (int c = 0; c < 4; ++c){
    const int idx = c*64 + lane;
    const float4 g  = ((const float4*)gamma)[idx];
    const float4 be = ((const float4*)beta)[idx];
    float4 o4;
    o4.x = s[c].x*rstd*g.x + be.x;
    o4.y = s[c].y*rstd*g.y + be.y;
    o4.z = s[c].z*rstd*g.z + be.z;
    o4.w = s[c].w*rstd*g.w + be.w;
    if (xoutF) ((float4*)(xoutF + (size_t)row*DM))[idx] = o4;
    ushort4 ob; ob.x=f2bf(o4.x); ob.y=f2bf(o4.y); ob.z=f2bf(o4.z); ob.w=f2bf(o4.w);
    ((ushort4*)(xb + (size_t)row*DM))[idx] = ob;
  }
}

// ---------------------------------------------------------------------------
extern "C" void kernel_launch(void* const* d_in, const int* in_sizes, int n_in,
                              void* d_out, int out_size, void* d_ws, size_t ws_size,
                              hipStream_t stream)
{
  const float* x    = (const float*)d_in[0];
  const float* Wq   = (const float*)d_in[1];
  const float* bq   = (const float*)d_in[2];
  const float* Wk   = (const float*)d_in[3];
  const float* bk   = (const float*)d_in[4];
  const float* Wv   = (const float*)d_in[5];
  const float* bv   = (const float*)d_in[6];
  const float* Wo   = (const float*)d_in[7];
  const float* bo   = (const float*)d_in[8];
  const float* W1   = (const float*)d_in[9];
  const float* b1   = (const float*)d_in[10];
  const float* W2   = (const float*)d_in[11];
  const float* b2   = (const float*)d_in[12];
  const float* gam  = (const float*)d_in[13];
  const float* bet  = (const float*)d_in[14];

  char* ws = (char*)d_ws;
  size_t off = 0;
  auto alloc = [&](size_t b){ void* p = ws + off; off = (off + b + 255) & ~(size_t)255; return p; };

  const size_t oneWT = 6ull*1048576*2;
  const size_t rest  = ((size_t)TOK*DM*2)   // xb
                     + ((size_t)TOK*3072*2) // qkv
                     + ((size_t)TOK*DM*2)   // avb
                     + ((size_t)TOK*DM*2)   // hbuf
                     + ((size_t)TOK*DM*2)   // ybuf
                     + 4096;
  const bool all4 = (4*oneWT + rest) <= ws_size;

  u16*   WT   = (u16*)  alloc(all4 ? 4*oneWT : oneWT);
  u16*   xb   = (u16*)  alloc((size_t)TOK*DM*2);
  u16*   qkv  = (u16*)  alloc((size_t)TOK*3072*2);
  u16*   avb  = (u16*)  alloc((size_t)TOK*DM*2);
  u16*   hbuf = (u16*)  alloc((size_t)TOK*DM*2);
  u16*   ybuf = (u16*)  alloc((size_t)TOK*DM*2);
  if (off > ws_size) return;  // insufficient scratch -> fail loudly (poisoned d_out)

  posenc_add<<<TOK, 256, 0, stream>>>(x, xb);
  if (all4)
    transpose6<<<4*1536, 256, 0, stream>>>(Wq, Wk, Wv, Wo, W1, W2, WT, 0);

  for (int l = 0; l < 4; ++l){
    u16* wt = all4 ? (WT + (size_t)l * 6 * 1048576) : WT;
    if (!all4)
      transpose6<<<1536, 256, 0, stream>>>(Wq, Wk, Wv, Wo, W1, W2, WT, l);
    // q,k,v = x@W{q,k,v}+b (q pre-scaled by 1/8)  [8-phase, grid 256 = 1 block/CU]
    qkv_gemm8<<<(TOK/QBM)*(3072/QBN), 512, 0, stream>>>(
        xb, wt, bq + l*1024, bk + l*1024, bv + l*1024, qkv);
    // channel attention  [grid 8192 x 256 thr]
    attn_chan<<<TOK*2, 256, 0, stream>>>(qkv, avb);
    // attn_out = av@Wo+bo -> bf16
    gemm_k1024<0><<<(TOK/BM)*(1024/64), 256, 0, stream>>>(
        avb, wt + 3ull*1048576, bo + l*1024, ybuf, TOK, 1024);
    residual_ln<<<TOK/4, 256, 0, stream>>>(ybuf, xb, gam + l*1024, bet + l*1024, nullptr, xb);
    // h = relu(x@W1+b1) -> bf16
    gemm_k1024<1><<<(TOK/BM)*(1024/64), 256, 0, stream>>>(
        xb, wt + 4ull*1048576, b1 + l*1024, hbuf, TOK, 1024);
    // y = h@W2+b2 -> bf16
    gemm_k1024<0><<<(TOK/BM)*(1024/64), 256, 0, stream>>>(
        hbuf, wt + 5ull*1048576, b2 + l*1024, ybuf, TOK, 1024);
    residual_ln<<<TOK/4, 256, 0, stream>>>(ybuf, xb, gam + l*1024, bet + l*1024,
                                           (l == 3) ? (float*)d_out : nullptr, xb);
  }
}